// Round 5
// baseline (851.841 us; speedup 1.0000x reference)
//
#include <hip/hip_runtime.h>

// B=8, N=HW=4096, D=512, I=256, DO=512
// ws (ushort offsets):
//   featT  @0        [b][n=4096][c=512] bf16 (k0a->k1); overlaid by out1 (k3->k4)
//   featV  @16777216 [b][mt=64][c=512][m=64] bf16 (k0a->k3)
//   phi_n  @33554432 [b][n][i=256] bf16 normalized (k1->k3)
//   theta_n@41943040 same (k1->k3)
//   wb_phi @50331648 [i=256][c=512] bf16 (k0b->k1)
//   wb_th  @50462720
//   weightT@50593792 [d=512][c=512] bf16 (k0c->k4)
// end 50855936 ushorts = 101.7 MB (<= proven 134 MB)

typedef short s8v __attribute__((ext_vector_type(8)));
typedef float f4v __attribute__((ext_vector_type(4)));

__device__ inline ushort f2bf(float x) {
  union { float f; unsigned u; } v; v.f = x;
  unsigned u = v.u + 0x7fff + ((v.u >> 16) & 1);
  return (ushort)(u >> 16);
}

// ---------- k0a: feat fp32 [b][c][m] -> featV blocked bf16 + featT bf16 ----
// grid 4096 = 8b x 8cb x 64mt, block 256
__global__ __launch_bounds__(256) void k0a(const float* __restrict__ feat,
                                           ushort* __restrict__ featT,
                                           ushort* __restrict__ featV) {
  int bid = blockIdx.x;
  int b = bid >> 9, cb = (bid >> 6) & 7, mt = bid & 63;
  int t = threadIdx.x;
  __shared__ ushort tile[64][72];

#pragma unroll
  for (int p = 0; p < 4; p++) {
    int ci = p * 16 + (t >> 4);
    int mi = (t & 15) * 4;
    float4 v = *(const float4*)&feat[((size_t)(b * 512 + cb * 64 + ci)) * 4096 + mt * 64 + mi];
    ushort4 u; u.x = f2bf(v.x); u.y = f2bf(v.y); u.z = f2bf(v.z); u.w = f2bf(v.w);
    *(ushort4*)&featV[((size_t)(b * 64 + mt) * 512 + cb * 64 + ci) * 64 + mi] = u;
    tile[ci][mi] = u.x; tile[ci][mi + 1] = u.y; tile[ci][mi + 2] = u.z; tile[ci][mi + 3] = u.w;
  }
  __syncthreads();
  int m = t >> 2, cs = (t & 3) * 16;
  ushort tmp[16];
#pragma unroll
  for (int j = 0; j < 16; j++) tmp[j] = tile[cs + j][m];
  ushort* dst = &featT[((size_t)(b * 4096 + mt * 64 + m)) * 512 + cb * 64 + cs];
  *(s8v*)dst = *(s8v*)&tmp[0];
  *(s8v*)(dst + 8) = *(s8v*)&tmp[8];
}

// ---------- k0b: cast phi_w / theta_w -> bf16 ------------------------------
__global__ __launch_bounds__(256) void k0b(const float* __restrict__ pw,
                                           const float* __restrict__ tw,
                                           ushort* __restrict__ wbp,
                                           ushort* __restrict__ wbt) {
  int bid = blockIdx.x;
  const float* src = (bid < 128) ? pw : tw;
  ushort* dst = (bid < 128) ? wbp : wbt;
  int idx = ((bid & 127) * 256 + threadIdx.x) * 4;
  float4 v = *(const float4*)&src[idx];
  ushort4 u; u.x = f2bf(v.x); u.y = f2bf(v.y); u.z = f2bf(v.z); u.w = f2bf(v.w);
  *(ushort4*)&dst[idx] = u;
}

// ---------- k0c: weight fp32 [c][d] -> weightT bf16 [d][c] -----------------
// grid 64 = 8cb x 8db
__global__ __launch_bounds__(256) void k0c(const float* __restrict__ w,
                                           ushort* __restrict__ wT) {
  int bid = blockIdx.x;
  int cb = bid >> 3, db = bid & 7;
  int t = threadIdx.x;
  __shared__ ushort tile[64][72];
#pragma unroll
  for (int p = 0; p < 4; p++) {
    int ci = p * 16 + (t >> 4);
    int di = (t & 15) * 4;
    float4 v = *(const float4*)&w[(size_t)(cb * 64 + ci) * 512 + db * 64 + di];
    tile[ci][di] = f2bf(v.x); tile[ci][di + 1] = f2bf(v.y);
    tile[ci][di + 2] = f2bf(v.z); tile[ci][di + 3] = f2bf(v.w);
  }
  __syncthreads();
  int d = t >> 2, cs = (t & 3) * 16;
  ushort tmp[16];
#pragma unroll
  for (int j = 0; j < 16; j++) tmp[j] = tile[cs + j][d];
  ushort* dst = &wT[(size_t)(db * 64 + d) * 512 + cb * 64 + cs];
  *(s8v*)dst = *(s8v*)&tmp[0];
  *(s8v*)(dst + 8) = *(s8v*)&tmp[8];
}

// ---------- k1: phi/theta MFMA GEMM + fused L2-normalize -> bf16 -----------
// grid 512 = 8b x 32nt x 2half, block 512 (8 waves x 16 n-rows, all 256 i)
__global__ __launch_bounds__(512) void k1_gemm(
    const ushort* __restrict__ featT, const ushort* __restrict__ wbp,
    const ushort* __restrict__ wbt, ushort* __restrict__ phi_n,
    ushort* __restrict__ theta_n) {
  int bid = blockIdx.x;
  int b = bid & 7;
  int rest = bid >> 3;
  int half = rest & 1;
  int nt = rest >> 1;
  const ushort* wb = half ? wbt : wbp;
  ushort* dst = half ? theta_n : phi_n;
  int t = threadIdx.x;
  int lane = t & 63, w = t >> 6;
  int col = lane & 15, quad = lane >> 4;
  int n0 = nt * 128;

  const ushort* abase =
      featT + ((size_t)(b * 4096 + n0 + w * 16 + col)) * 512 + quad * 8;

  f4v acc[16];
#pragma unroll
  for (int i = 0; i < 16; i++) acc[i] = (f4v){0.f, 0.f, 0.f, 0.f};

#pragma unroll 2
  for (int kc = 0; kc < 16; kc++) {
    s8v a = *(const s8v*)(abase + kc * 32);
#pragma unroll
    for (int it = 0; it < 16; it++) {
      s8v bf = *(const s8v*)(wb + (size_t)(it * 16 + col) * 512 + kc * 32 + quad * 8);
      acc[it] = __builtin_amdgcn_mfma_f32_16x16x32_bf16(a, bf, acc[it], 0, 0, 0);
    }
  }
  // fused normalize: lane holds rows n = w*16 + quad*4 + reg, cols i = it*16+col
  float rinv[4];
#pragma unroll
  for (int reg = 0; reg < 4; reg++) {
    float ss = 0.f;
#pragma unroll
    for (int it = 0; it < 16; it++) ss += acc[it][reg] * acc[it][reg];
    ss += __shfl_xor(ss, 1); ss += __shfl_xor(ss, 2);
    ss += __shfl_xor(ss, 4); ss += __shfl_xor(ss, 8);
    rinv[reg] = rsqrtf(ss);
  }
#pragma unroll
  for (int it = 0; it < 16; it++) {
#pragma unroll
    for (int reg = 0; reg < 4; reg++) {
      dst[((size_t)(b * 4096 + n0 + w * 16 + quad * 4 + reg)) * 256 + it * 16 + col] =
          f2bf(acc[it][reg] * rinv[reg]);
    }
  }
}

// ---------- k3: MFMA flash attention v6 — 16-wave block, <=128 regs/wave ---
// grid 512 = 8b(LSB) x 64qt, block 1024 = 16 waves.
// Occupancy model (rounds 0-4): gfx950 unified RF -> occupancy set by
// arch VGPR + AGPR. 8-wave layout = 184 combined -> 2 waves/SIMD (22%).
// This layout halves per-wave state: qf 32 + kreg 8 + v 16 + acc(AGPR) 32
// + misc ~25 => ~115 combined <= 128 -> 4 waves/SIMD = 16 waves/CU.
// __launch_bounds__(1024,4) = cap 128 combined (matches budget; rounds 2/3
// failed because cap 128 was applied to a 184-live kernel).
// Roles: QK wave (mh4=w&3 m-col group, rq=w>>2 q-row set of 16): 8 MFMA.
//        PV  wave owns c [w*32,+32): 16 MFMA, acc[8].
// K dbuf (64KB) + P dbuf (16KB) + dred = 82.9KB, SINGLE barrier per m-tile
// (round-1 proven protocol).
__global__ __launch_bounds__(1024, 4) void k3_attn(
    const ushort* __restrict__ phi_n, const ushort* __restrict__ theta_n,
    const ushort* __restrict__ featV, ushort* __restrict__ out1) {
  int bid = blockIdx.x;
  int b = bid & 7;
  int n0 = (bid >> 3) << 6;
  int t = threadIdx.x;
  int lane = t & 63, w = t >> 6;
  int col = lane & 15, quad = lane >> 4;
  int mh4 = w & 3, rq = w >> 2;
  int l32 = lane & 31, h32 = lane >> 5;
  int cs = col & 7;

  __shared__ __align__(16) ushort ks[2 * 16384];  // [buf][row*256 + (chunk^(row&7))*8]
  __shared__ __align__(16) ushort ps[2 * 4096];   // [buf][n*64 + (chunk^(n&7))*8]
  __shared__ float dred[4 * 64];                  // [mh4][n]

  // Q A-frags, ONE 16-row set: rows rq*16 + col, k = f*32 + quad*8
  s8v qf[8];
  {
    const ushort* qa = phi_n + ((size_t)(b * 4096 + n0 + rq * 16 + col)) * 256 + quad * 8;
#pragma unroll
    for (int f = 0; f < 8; f++) qf[f] = *(const s8v*)(qa + f * 32);
  }

  const ushort* thb = theta_n + (size_t)b * 4096 * 256;
  const ushort* vbb = featV + (size_t)b * 64 * 512 * 64 + (size_t)(w * 32) * 64;

  f4v acc[8];
#pragma unroll
  for (int i = 0; i < 8; i++) acc[i] = (f4v){0.f, 0.f, 0.f, 0.f};
  float denp[4] = {0.f, 0.f, 0.f, 0.f};

  // stage tile 0 into ks[0]: 4 rows per wave (16 waves x 4 = 64)
#pragma unroll
  for (int u = 0; u < 2; u++) {
    int row = w * 4 + u * 2 + h32;
    s8v val = *(const s8v*)(thb + (size_t)row * 256 + l32 * 8);
    *(s8v*)(ks + row * 256 + ((l32 ^ (row & 7)) * 8)) = val;
  }
  __syncthreads();

#pragma unroll 1
  for (int mt = 0; mt < 64; mt++) {
    const ushort* kc_ = ks + (mt & 1) * 16384;
    ushort* kn_ = ks + ((mt & 1) ^ 1) * 16384;
    ushort* pw_ = ps + (mt & 1) * 4096;

    // prefetch next K tile into regs (written to LDS just before the barrier)
    s8v kreg[2];
    if (mt < 63) {
      int m1 = (mt + 1) << 6;
#pragma unroll
      for (int u = 0; u < 2; u++) {
        int row = w * 4 + u * 2 + h32;
        kreg[u] = *(const s8v*)(thb + (size_t)(m1 + row) * 256 + l32 * 8);
      }
    }
    // V B-frags for this tile (blocked layout), wave's 32-c range
    s8v v0[2], v1[2];
    {
      const ushort* vb = vbb + (size_t)mt * 32768;
#pragma unroll
      for (int ct = 0; ct < 2; ct++) {
        const ushort* p = vb + (ct * 16 + col) * 64 + quad * 8;
        v0[ct] = *(const s8v*)p;
        v1[ct] = *(const s8v*)(p + 32);
      }
    }

    // QK: 16 m-cols (mh4*16+col) x 16 q-rows (rq set); 2 chains of 4
    f4v sv0 = (f4v){0.f, 0.f, 0.f, 0.f};
    f4v sv1 = (f4v){0.f, 0.f, 0.f, 0.f};
    {
      const ushort* kb = kc_ + (mh4 * 16 + col) * 256;
      __builtin_amdgcn_s_setprio(1);
#pragma unroll
      for (int kk = 0; kk < 4; kk++) {
        int pos0 = ((kk * 4 + quad) ^ cs) * 8;
        int pos1 = (((kk + 4) * 4 + quad) ^ cs) * 8;
        s8v b0 = *(const s8v*)(kb + pos0);
        s8v b1 = *(const s8v*)(kb + pos1);
        sv0 = __builtin_amdgcn_mfma_f32_16x16x32_bf16(qf[kk], b0, sv0, 0, 0, 0);
        sv1 = __builtin_amdgcn_mfma_f32_16x16x32_bf16(qf[kk + 4], b1, sv1, 0, 0, 0);
      }
      __builtin_amdgcn_s_setprio(0);
    }

    float pA[4];
#pragma unroll
    for (int r = 0; r < 4; r++) {
      pA[r] = __expf(sv0[r] + sv1[r]);
      denp[r] += pA[r];
    }

    // P -> LDS (swizzled, double-buffered): rows n = rq*16+quad*4+r
    {
      int j0 = mh4 * 2 + (col >> 3);
#pragma unroll
      for (int r = 0; r < 4; r++) {
        int n = rq * 16 + quad * 4 + r;
        pw_[n * 64 + ((j0 ^ (n & 7)) * 8) + cs] = f2bf(pA[r]);
      }
    }
    // write next K tile to other buffer
    if (mt < 63) {
#pragma unroll
      for (int u = 0; u < 2; u++) {
        int row = w * 4 + u * 2 + h32;
        *(s8v*)(kn_ + row * 256 + ((l32 ^ (row & 7)) * 8)) = kreg[u];
      }
    }
    __syncthreads();  // single barrier: ps[buf] + ks[next] ready

    // PV: A = P (all 4 rowsets), B = v0/v1 (this wave's 32-c range)
    __builtin_amdgcn_s_setprio(1);
#pragma unroll
    for (int rs = 0; rs < 4; rs++) {
      const ushort* pb = pw_ + (rs * 16 + col) * 64;
      s8v pf0 = *(const s8v*)(pb + ((quad ^ cs) * 8));
      s8v pf1 = *(const s8v*)(pb + (((quad + 4) ^ cs) * 8));
#pragma unroll
      for (int ct = 0; ct < 2; ct++) {
        acc[rs * 2 + ct] =
            __builtin_amdgcn_mfma_f32_16x16x32_bf16(pf0, v0[ct], acc[rs * 2 + ct], 0, 0, 0);
        acc[rs * 2 + ct] =
            __builtin_amdgcn_mfma_f32_16x16x32_bf16(pf1, v1[ct], acc[rs * 2 + ct], 0, 0, 0);
      }
    }
    __builtin_amdgcn_s_setprio(0);
  }

  // denominator: reduce over 16-col group, then across the 4 mh4 groups
#pragma unroll
  for (int r = 0; r < 4; r++) {
    float d = denp[r];
    d += __shfl_xor(d, 1); d += __shfl_xor(d, 2);
    d += __shfl_xor(d, 4); d += __shfl_xor(d, 8);
    denp[r] = d;
  }
  if (col == 0) {
#pragma unroll
    for (int r = 0; r < 4; r++) dred[mh4 * 64 + rq * 16 + quad * 4 + r] = denp[r];
  }
  __syncthreads();
  if (t < 64) dred[t] = 1.0f / (dred[t] + dred[64 + t] + dred[128 + t] + dred[192 + t]);
  __syncthreads();

  // store out1 bf16 [n][c]: D[n=rs*16+quad*4+reg][c=w*32+ct*16+col]
#pragma unroll
  for (int rs = 0; rs < 4; rs++) {
#pragma unroll
    for (int ct = 0; ct < 2; ct++) {
#pragma unroll
      for (int reg = 0; reg < 4; reg++) {
        int n = rs * 16 + quad * 4 + reg;
        out1[((size_t)(b * 4096 + n0 + n)) * 512 + w * 32 + ct * 16 + col] =
            f2bf(acc[rs * 2 + ct][reg] * dred[n]);
      }
    }
  }
}

// ---------- k4: out = relu(weightT_bf @ out1^T) stored [b][d][n] fp32 ------
// grid 512 = 8b x 4dt x 16nt, block 512 = 8 waves (dw=w&1 -> 64d, nw=w>>1 -> 64n)
__global__ __launch_bounds__(512) void k4_out(
    const ushort* __restrict__ out1, const ushort* __restrict__ wT,
    float* __restrict__ out) {
  int bid = blockIdx.x;
  int b = bid & 7;
  int rest = bid >> 3;
  int dt = rest & 3;
  int nt = rest >> 2;
  int t = threadIdx.x;
  int lane = t & 63, w = t >> 6;
  int col = lane & 15, quad = lane >> 4;
  int dw = w & 1, nw = w >> 1;
  int d0 = dt * 128 + dw * 64;
  int n0 = nt * 256 + nw * 64;

  f4v acc[16];
#pragma unroll
  for (int i = 0; i < 16; i++) acc[i] = (f4v){0.f, 0.f, 0.f, 0.f};

#pragma unroll 2
  for (int kc = 0; kc < 16; kc++) {
    s8v af[4], bf[4];
#pragma unroll
    for (int rs = 0; rs < 4; rs++)
      af[rs] = *(const s8v*)(wT + (size_t)(d0 + rs * 16 + col) * 512 + kc * 32 + quad * 8);
#pragma unroll
    for (int ct = 0; ct < 4; ct++)
      bf[ct] = *(const s8v*)(out1 + ((size_t)(b * 4096 + n0 + ct * 16 + col)) * 512 +
                             kc * 32 + quad * 8);
#pragma unroll
    for (int rs = 0; rs < 4; rs++)
#pragma unroll
      for (int ct = 0; ct < 4; ct++)
        acc[rs * 4 + ct] =
            __builtin_amdgcn_mfma_f32_16x16x32_bf16(af[rs], bf[ct], acc[rs * 4 + ct], 0, 0, 0);
  }
#pragma unroll
  for (int rs = 0; rs < 4; rs++) {
#pragma unroll
    for (int ct = 0; ct < 4; ct++) {
#pragma unroll
      for (int reg = 0; reg < 4; reg++) {
        int d = d0 + rs * 16 + quad * 4 + reg;
        int n = n0 + ct * 16 + col;
        out[((size_t)(b * 512 + d)) * 4096 + n] = fmaxf(acc[rs * 4 + ct][reg], 0.f);
      }
    }
  }
}

extern "C" void kernel_launch(void* const* d_in, const int* in_sizes, int n_in,
                              void* d_out, int out_size, void* d_ws, size_t ws_size,
                              hipStream_t stream) {
  const float* feat    = (const float*)d_in[0];
  const float* phi_w   = (const float*)d_in[1];
  const float* theta_w = (const float*)d_in[2];
  const float* weight  = (const float*)d_in[3];
  float* out = (float*)d_out;

  ushort* wsu = (ushort*)d_ws;
  ushort* featT   = wsu;                    // dead after k1 -> reused as out1
  ushort* featV   = wsu + 16777216;
  ushort* phi_n   = wsu + 33554432;
  ushort* theta_n = wsu + 41943040;
  ushort* wbp     = wsu + 50331648;
  ushort* wbt     = wsu + 50462720;
  ushort* weightT = wsu + 50593792;
  ushort* out1    = wsu;                    // overlays featT

  k0a<<<dim3(4096), dim3(256), 0, stream>>>(feat, featT, featV);
  k0b<<<dim3(256), dim3(256), 0, stream>>>(phi_w, theta_w, wbp, wbt);
  k0c<<<dim3(64), dim3(256), 0, stream>>>(weight, weightT);
  k1_gemm<<<dim3(512), dim3(512), 0, stream>>>(featT, wbp, wbt, phi_n, theta_n);
  k3_attn<<<dim3(512), dim3(1024), 0, stream>>>(phi_n, theta_n, featV, out1);
  k4_out<<<dim3(512), dim3(512), 0, stream>>>(out1, weightT, out);
}

// Round 6
// 698.169 us; speedup vs baseline: 1.2201x; 1.2201x over previous
//
#include <hip/hip_runtime.h>

// B=8, N=HW=4096, D=512, I=256, DO=512
// ws (ushort offsets):
//   featT  @0        [b][n=4096][c=512] bf16 (k0a->k1); overlaid by out1 (k3->k4)
//   featV  @16777216 [b][mt=64][c=512][m=64] bf16 (k0a->k3)
//   phi_n  @33554432 [b][n][i=256] bf16 normalized (k1->k3)
//   theta_n@41943040 same (k1->k3)
//   wb_phi @50331648 [i=256][c=512] bf16 (k0b->k1)
//   wb_th  @50462720
//   weightT@50593792 [d=512][c=512] bf16 (k0c->k4)
// end 50855936 ushorts = 101.7 MB (<= proven 134 MB)

typedef short s8v __attribute__((ext_vector_type(8)));
typedef float f4v __attribute__((ext_vector_type(4)));

__device__ inline ushort f2bf(float x) {
  union { float f; unsigned u; } v; v.f = x;
  unsigned u = v.u + 0x7fff + ((v.u >> 16) & 1);
  return (ushort)(u >> 16);
}

// 16B global -> LDS direct DMA (no VGPR round-trip). gptr per-lane, lptr
// wave-uniform; HW writes lptr + lane*16.
__device__ inline void gload16(const ushort* g, ushort* l) {
  __builtin_amdgcn_global_load_lds(
      (const __attribute__((address_space(1))) unsigned int*)g,
      (__attribute__((address_space(3))) unsigned int*)l, 16, 0, 0);
}

// ---------- k0a: feat fp32 [b][c][m] -> featV blocked bf16 + featT bf16 ----
// grid 4096 = 8b x 8cb x 64mt, block 256
__global__ __launch_bounds__(256) void k0a(const float* __restrict__ feat,
                                           ushort* __restrict__ featT,
                                           ushort* __restrict__ featV) {
  int bid = blockIdx.x;
  int b = bid >> 9, cb = (bid >> 6) & 7, mt = bid & 63;
  int t = threadIdx.x;
  __shared__ ushort tile[64][72];

#pragma unroll
  for (int p = 0; p < 4; p++) {
    int ci = p * 16 + (t >> 4);
    int mi = (t & 15) * 4;
    float4 v = *(const float4*)&feat[((size_t)(b * 512 + cb * 64 + ci)) * 4096 + mt * 64 + mi];
    ushort4 u; u.x = f2bf(v.x); u.y = f2bf(v.y); u.z = f2bf(v.z); u.w = f2bf(v.w);
    *(ushort4*)&featV[((size_t)(b * 64 + mt) * 512 + cb * 64 + ci) * 64 + mi] = u;
    tile[ci][mi] = u.x; tile[ci][mi + 1] = u.y; tile[ci][mi + 2] = u.z; tile[ci][mi + 3] = u.w;
  }
  __syncthreads();
  int m = t >> 2, cs = (t & 3) * 16;
  ushort tmp[16];
#pragma unroll
  for (int j = 0; j < 16; j++) tmp[j] = tile[cs + j][m];
  ushort* dst = &featT[((size_t)(b * 4096 + mt * 64 + m)) * 512 + cb * 64 + cs];
  *(s8v*)dst = *(s8v*)&tmp[0];
  *(s8v*)(dst + 8) = *(s8v*)&tmp[8];
}

// ---------- k0b: cast phi_w / theta_w -> bf16 ------------------------------
__global__ __launch_bounds__(256) void k0b(const float* __restrict__ pw,
                                           const float* __restrict__ tw,
                                           ushort* __restrict__ wbp,
                                           ushort* __restrict__ wbt) {
  int bid = blockIdx.x;
  const float* src = (bid < 128) ? pw : tw;
  ushort* dst = (bid < 128) ? wbp : wbt;
  int idx = ((bid & 127) * 256 + threadIdx.x) * 4;
  float4 v = *(const float4*)&src[idx];
  ushort4 u; u.x = f2bf(v.x); u.y = f2bf(v.y); u.z = f2bf(v.z); u.w = f2bf(v.w);
  *(ushort4*)&dst[idx] = u;
}

// ---------- k0c: weight fp32 [c][d] -> weightT bf16 [d][c] -----------------
// grid 64 = 8cb x 8db
__global__ __launch_bounds__(256) void k0c(const float* __restrict__ w,
                                           ushort* __restrict__ wT) {
  int bid = blockIdx.x;
  int cb = bid >> 3, db = bid & 7;
  int t = threadIdx.x;
  __shared__ ushort tile[64][72];
#pragma unroll
  for (int p = 0; p < 4; p++) {
    int ci = p * 16 + (t >> 4);
    int di = (t & 15) * 4;
    float4 v = *(const float4*)&w[(size_t)(cb * 64 + ci) * 512 + db * 64 + di];
    tile[ci][di] = f2bf(v.x); tile[ci][di + 1] = f2bf(v.y);
    tile[ci][di + 2] = f2bf(v.z); tile[ci][di + 3] = f2bf(v.w);
  }
  __syncthreads();
  int d = t >> 2, cs = (t & 3) * 16;
  ushort tmp[16];
#pragma unroll
  for (int j = 0; j < 16; j++) tmp[j] = tile[cs + j][d];
  ushort* dst = &wT[(size_t)(db * 64 + d) * 512 + cb * 64 + cs];
  *(s8v*)dst = *(s8v*)&tmp[0];
  *(s8v*)(dst + 8) = *(s8v*)&tmp[8];
}

// ---------- k1: phi/theta MFMA GEMM + fused L2-normalize -> bf16 -----------
// grid 512 = 8b x 32nt x 2half, block 512 (8 waves x 16 n-rows, all 256 i)
__global__ __launch_bounds__(512) void k1_gemm(
    const ushort* __restrict__ featT, const ushort* __restrict__ wbp,
    const ushort* __restrict__ wbt, ushort* __restrict__ phi_n,
    ushort* __restrict__ theta_n) {
  int bid = blockIdx.x;
  int b = bid & 7;
  int rest = bid >> 3;
  int half = rest & 1;
  int nt = rest >> 1;
  const ushort* wb = half ? wbt : wbp;
  ushort* dst = half ? theta_n : phi_n;
  int t = threadIdx.x;
  int lane = t & 63, w = t >> 6;
  int col = lane & 15, quad = lane >> 4;
  int n0 = nt * 128;

  const ushort* abase =
      featT + ((size_t)(b * 4096 + n0 + w * 16 + col)) * 512 + quad * 8;

  f4v acc[16];
#pragma unroll
  for (int i = 0; i < 16; i++) acc[i] = (f4v){0.f, 0.f, 0.f, 0.f};

#pragma unroll 2
  for (int kc = 0; kc < 16; kc++) {
    s8v a = *(const s8v*)(abase + kc * 32);
#pragma unroll
    for (int it = 0; it < 16; it++) {
      s8v bf = *(const s8v*)(wb + (size_t)(it * 16 + col) * 512 + kc * 32 + quad * 8);
      acc[it] = __builtin_amdgcn_mfma_f32_16x16x32_bf16(a, bf, acc[it], 0, 0, 0);
    }
  }
  // fused normalize: lane holds rows n = w*16 + quad*4 + reg, cols i = it*16+col
  float rinv[4];
#pragma unroll
  for (int reg = 0; reg < 4; reg++) {
    float ss = 0.f;
#pragma unroll
    for (int it = 0; it < 16; it++) ss += acc[it][reg] * acc[it][reg];
    ss += __shfl_xor(ss, 1); ss += __shfl_xor(ss, 2);
    ss += __shfl_xor(ss, 4); ss += __shfl_xor(ss, 8);
    rinv[reg] = rsqrtf(ss);
  }
#pragma unroll
  for (int it = 0; it < 16; it++) {
#pragma unroll
    for (int reg = 0; reg < 4; reg++) {
      dst[((size_t)(b * 4096 + n0 + w * 16 + quad * 4 + reg)) * 256 + it * 16 + col] =
          f2bf(acc[it][reg] * rinv[reg]);
    }
  }
}

// ---------- k3: MFMA flash attention v7 — 16 waves + global_load_lds K -----
// grid 512 = 8b(LSB) x 64qt, block 1024 = 16 waves, 4 waves/SIMD.
// R5 failed on VGPR spill (needed ~140 > 128-combined cap). This version
// deletes the whole K register pipeline: K staged via global_load_lds DMA
// (2 instrs/wave, no kreg, no ds_write temps). LDS final state identical to
// R5 (linear DMA dest + inverse-swizzled per-lane global SOURCE, T21), so
// all read paths are R5's harness-verified ones.
// Budget: qf 32 + v 16 + acc 32(AGPR) + sv 8 + pA/denp 8 + addr ~12 = ~108.
// Roles: QK wave (mh4=w&3 m-cols, rq=w>>2 q-set of 16): 8 MFMA.
//        PV  wave owns c [w*32,+32): 16 MFMA, acc[8].
// K dbuf (64KB) + P dbuf (16KB) + dred = 81KB, single barrier per m-tile.
__global__ __launch_bounds__(1024, 4) void k3_attn(
    const ushort* __restrict__ phi_n, const ushort* __restrict__ theta_n,
    const ushort* __restrict__ featV, ushort* __restrict__ out1) {
  int bid = blockIdx.x;
  int b = bid & 7;
  int n0 = (bid >> 3) << 6;
  int t = threadIdx.x;
  int lane = t & 63, w = t >> 6;
  int col = lane & 15, quad = lane >> 4;
  int mh4 = w & 3, rq = w >> 2;
  int l32 = lane & 31, h32 = lane >> 5;
  int cs = col & 7;

  __shared__ __align__(16) ushort ks[2 * 16384];  // [buf][row*256 + pos*8]; pos p holds chunk p^(row&7)
  __shared__ __align__(16) ushort ps[2 * 4096];   // [buf][n*64 + (chunk^(n&7))*8]
  __shared__ float dred[4 * 64];                  // [mh4][n]

  // Q A-frags, ONE 16-row set: rows rq*16 + col, k = f*32 + quad*8
  s8v qf[8];
  {
    const ushort* qa = phi_n + ((size_t)(b * 4096 + n0 + rq * 16 + col)) * 256 + quad * 8;
#pragma unroll
    for (int f = 0; f < 8; f++) qf[f] = *(const s8v*)(qa + f * 32);
  }

  const ushort* thb = theta_n + (size_t)b * 4096 * 256;
  const ushort* vbb = featV + (size_t)b * 64 * 512 * 64 + (size_t)(w * 32) * 64;

  // per-lane K staging source offset pieces (row parity chooses xor of h32)
  // wave stages rows w*4 + {0,1,2,3}; instr u covers rows w*4+u*2+h32.
  f4v acc[8];
#pragma unroll
  for (int i = 0; i < 8; i++) acc[i] = (f4v){0.f, 0.f, 0.f, 0.f};
  float denp[4] = {0.f, 0.f, 0.f, 0.f};

  // stage tile 0 into ks[0] via DMA: dest linear, source chunk l32^(row&7)
#pragma unroll
  for (int u = 0; u < 2; u++) {
    int row0 = w * 4 + u * 2;          // wave-uniform
    int row = row0 + h32;              // per-lane
    gload16(thb + (size_t)row * 256 + ((l32 ^ (row & 7)) * 8), ks + row0 * 256);
  }
  __syncthreads();  // drains vmcnt -> tile 0 visible

#pragma unroll 1
  for (int mt = 0; mt < 64; mt++) {
    const ushort* kc_ = ks + (mt & 1) * 16384;
    ushort* kn_ = ks + ((mt & 1) ^ 1) * 16384;
    ushort* pw_ = ps + (mt & 1) * 4096;

    // issue next K tile DMA (lands before next barrier's vmcnt drain)
    if (mt < 63) {
      int m1 = (mt + 1) << 6;
#pragma unroll
      for (int u = 0; u < 2; u++) {
        int row0 = w * 4 + u * 2;
        int row = row0 + h32;
        gload16(thb + (size_t)(m1 + row) * 256 + ((l32 ^ (row & 7)) * 8),
                kn_ + row0 * 256);
      }
    }
    // V B-frags for this tile (blocked layout), wave's 32-c range
    s8v v0[2], v1[2];
    {
      const ushort* vb = vbb + (size_t)mt * 32768;
#pragma unroll
      for (int ct = 0; ct < 2; ct++) {
        const ushort* p = vb + (ct * 16 + col) * 64 + quad * 8;
        v0[ct] = *(const s8v*)p;
        v1[ct] = *(const s8v*)(p + 32);
      }
    }

    // QK: 16 m-cols (mh4*16+col) x 16 q-rows (rq set); 2 chains of 4
    f4v sv0 = (f4v){0.f, 0.f, 0.f, 0.f};
    f4v sv1 = (f4v){0.f, 0.f, 0.f, 0.f};
    {
      const ushort* kb = kc_ + (mh4 * 16 + col) * 256;
      __builtin_amdgcn_s_setprio(1);
#pragma unroll
      for (int kk = 0; kk < 4; kk++) {
        int pos0 = ((kk * 4 + quad) ^ cs) * 8;
        int pos1 = (((kk + 4) * 4 + quad) ^ cs) * 8;
        s8v b0 = *(const s8v*)(kb + pos0);
        s8v b1 = *(const s8v*)(kb + pos1);
        sv0 = __builtin_amdgcn_mfma_f32_16x16x32_bf16(qf[kk], b0, sv0, 0, 0, 0);
        sv1 = __builtin_amdgcn_mfma_f32_16x16x32_bf16(qf[kk + 4], b1, sv1, 0, 0, 0);
      }
      __builtin_amdgcn_s_setprio(0);
    }

    float pA[4];
#pragma unroll
    for (int r = 0; r < 4; r++) {
      pA[r] = __expf(sv0[r] + sv1[r]);
      denp[r] += pA[r];
    }

    // P -> LDS (swizzled, double-buffered): rows n = rq*16+quad*4+r
    {
      int j0 = mh4 * 2 + (col >> 3);
#pragma unroll
      for (int r = 0; r < 4; r++) {
        int n = rq * 16 + quad * 4 + r;
        pw_[n * 64 + ((j0 ^ (n & 7)) * 8) + cs] = f2bf(pA[r]);
      }
    }
    __syncthreads();  // single barrier: ps[buf] ready + K DMA drained

    // PV: A = P (all 4 rowsets), B = v0/v1 (this wave's 32-c range)
    __builtin_amdgcn_s_setprio(1);
#pragma unroll
    for (int rs = 0; rs < 4; rs++) {
      const ushort* pb = pw_ + (rs * 16 + col) * 64;
      s8v pf0 = *(const s8v*)(pb + ((quad ^ cs) * 8));
      s8v pf1 = *(const s8v*)(pb + (((quad + 4) ^ cs) * 8));
#pragma unroll
      for (int ct = 0; ct < 2; ct++) {
        acc[rs * 2 + ct] =
            __builtin_amdgcn_mfma_f32_16x16x32_bf16(pf0, v0[ct], acc[rs * 2 + ct], 0, 0, 0);
        acc[rs * 2 + ct] =
            __builtin_amdgcn_mfma_f32_16x16x32_bf16(pf1, v1[ct], acc[rs * 2 + ct], 0, 0, 0);
      }
    }
    __builtin_amdgcn_s_setprio(0);
  }

  // denominator: reduce over 16-col group, then across the 4 mh4 groups
#pragma unroll
  for (int r = 0; r < 4; r++) {
    float d = denp[r];
    d += __shfl_xor(d, 1); d += __shfl_xor(d, 2);
    d += __shfl_xor(d, 4); d += __shfl_xor(d, 8);
    denp[r] = d;
  }
  if (col == 0) {
#pragma unroll
    for (int r = 0; r < 4; r++) dred[mh4 * 64 + rq * 16 + quad * 4 + r] = denp[r];
  }
  __syncthreads();
  if (t < 64) dred[t] = 1.0f / (dred[t] + dred[64 + t] + dred[128 + t] + dred[192 + t]);
  __syncthreads();

  // store out1 bf16 [n][c]: D[n=rs*16+quad*4+reg][c=w*32+ct*16+col]
#pragma unroll
  for (int rs = 0; rs < 4; rs++) {
#pragma unroll
    for (int ct = 0; ct < 2; ct++) {
#pragma unroll
      for (int reg = 0; reg < 4; reg++) {
        int n = rs * 16 + quad * 4 + reg;
        out1[((size_t)(b * 4096 + n0 + n)) * 512 + w * 32 + ct * 16 + col] =
            f2bf(acc[rs * 2 + ct][reg] * dred[n]);
      }
    }
  }
}

// ---------- k4: out = relu(weightT_bf @ out1^T) stored [b][d][n] fp32 ------
// grid 512 = 8b x 4dt x 16nt, block 512 = 8 waves (dw=w&1 -> 64d, nw=w>>1 -> 64n)
__global__ __launch_bounds__(512) void k4_out(
    const ushort* __restrict__ out1, const ushort* __restrict__ wT,
    float* __restrict__ out) {
  int bid = blockIdx.x;
  int b = bid & 7;
  int rest = bid >> 3;
  int dt = rest & 3;
  int nt = rest >> 2;
  int t = threadIdx.x;
  int lane = t & 63, w = t >> 6;
  int col = lane & 15, quad = lane >> 4;
  int dw = w & 1, nw = w >> 1;
  int d0 = dt * 128 + dw * 64;
  int n0 = nt * 256 + nw * 64;

  f4v acc[16];
#pragma unroll
  for (int i = 0; i < 16; i++) acc[i] = (f4v){0.f, 0.f, 0.f, 0.f};

#pragma unroll 2
  for (int kc = 0; kc < 16; kc++) {
    s8v af[4], bf[4];
#pragma unroll
    for (int rs = 0; rs < 4; rs++)
      af[rs] = *(const s8v*)(wT + (size_t)(d0 + rs * 16 + col) * 512 + kc * 32 + quad * 8);
#pragma unroll
    for (int ct = 0; ct < 4; ct++)
      bf[ct] = *(const s8v*)(out1 + ((size_t)(b * 4096 + n0 + ct * 16 + col)) * 512 +
                             kc * 32 + quad * 8);
#pragma unroll
    for (int rs = 0; rs < 4; rs++)
#pragma unroll
      for (int ct = 0; ct < 4; ct++)
        acc[rs * 4 + ct] =
            __builtin_amdgcn_mfma_f32_16x16x32_bf16(af[rs], bf[ct], acc[rs * 4 + ct], 0, 0, 0);
  }
#pragma unroll
  for (int rs = 0; rs < 4; rs++) {
#pragma unroll
    for (int ct = 0; ct < 4; ct++) {
#pragma unroll
      for (int reg = 0; reg < 4; reg++) {
        int d = d0 + rs * 16 + quad * 4 + reg;
        int n = n0 + ct * 16 + col;
        out[((size_t)(b * 512 + d)) * 4096 + n] = fmaxf(acc[rs * 4 + ct][reg], 0.f);
      }
    }
  }
}

extern "C" void kernel_launch(void* const* d_in, const int* in_sizes, int n_in,
                              void* d_out, int out_size, void* d_ws, size_t ws_size,
                              hipStream_t stream) {
  const float* feat    = (const float*)d_in[0];
  const float* phi_w   = (const float*)d_in[1];
  const float* theta_w = (const float*)d_in[2];
  const float* weight  = (const float*)d_in[3];
  float* out = (float*)d_out;

  ushort* wsu = (ushort*)d_ws;
  ushort* featT   = wsu;                    // dead after k1 -> reused as out1
  ushort* featV   = wsu + 16777216;
  ushort* phi_n   = wsu + 33554432;
  ushort* theta_n = wsu + 41943040;
  ushort* wbp     = wsu + 50331648;
  ushort* wbt     = wsu + 50462720;
  ushort* weightT = wsu + 50593792;
  ushort* out1    = wsu;                    // overlays featT

  k0a<<<dim3(4096), dim3(256), 0, stream>>>(feat, featT, featV);
  k0b<<<dim3(256), dim3(256), 0, stream>>>(phi_w, theta_w, wbp, wbt);
  k0c<<<dim3(64), dim3(256), 0, stream>>>(weight, weightT);
  k1_gemm<<<dim3(512), dim3(512), 0, stream>>>(featT, wbp, wbt, phi_n, theta_n);
  k3_attn<<<dim3(512), dim3(1024), 0, stream>>>(phi_n, theta_n, featV, out1);
  k4_out<<<dim3(512), dim3(512), 0, stream>>>(out1, weightT, out);
}